// Round 7
// baseline (299.622 us; speedup 1.0000x reference)
//
#include <hip/hip_runtime.h>
#include <stdint.h>

#define AS1 __attribute__((address_space(1)))
#define AS3 __attribute__((address_space(3)))

typedef __bf16 bf16x8 __attribute__((ext_vector_type(8)));
typedef float f32x16 __attribute__((ext_vector_type(16)));

__device__ __forceinline__ unsigned short f2bf(float f) {
  unsigned u = __float_as_uint(f);
  u += 0x7FFF + ((u >> 16) & 1);   // round-to-nearest-even
  return (unsigned short)(u >> 16);
}

// ---------------- merged fp32 -> bf16 cast for X, W_in, W_out (grid-stride) ----------------
__global__ __launch_bounds__(256) void cast_all_kernel(const float* __restrict__ X,
                                                       const float* __restrict__ Wi,
                                                       const float* __restrict__ Wo,
                                                       unsigned short* __restrict__ out) {
  const int c1 = 2097152;            // X groups of 4
  const int c2 = 786432;             // W_in groups
  const int c3 = 262144;             // W_out groups
  const int total = c1 + c2 + c3;
  for (int i = blockIdx.x * 256 + threadIdx.x; i < total; i += 2048 * 256) {
    const float* src;
    int j = i;
    if (i < c1) src = X;
    else if (i < c1 + c2) { src = Wi; j = i - c1; }
    else { src = Wo; j = i - c1 - c2; }
    float4 v = reinterpret_cast<const float4*>(src)[j];
    ushort4 o;
    o.x = f2bf(v.x); o.y = f2bf(v.y); o.z = f2bf(v.z); o.w = f2bf(v.w);
    reinterpret_cast<ushort4*>(out)[i] = o;
  }
}

// ---------------- GEMM-BT 128x128, BK=128, 64-bank-aware conflict-free swizzle ----------------
// C[m][n] = sum_k A[m][k]*B[n][k]. 4 waves of 2x2 32x32x16 MFMA.
// BK=128: 8 K-steps for K=1024 -> half the barrier+drain count vs BK=64. LDS 64 KB.
// Bank model (derived R0/R4/R6 counter signatures): effective bank = addr[7:2]
// (64 x 4B, 256 B/clock). Conflict-free requires each 16-lane b128 group to cover
// 16 distinct 16-B chunks within a 256-B window.
// Swizzle: key4(row) = ((row&1)<<3) | ((row>>1)&7)  -- bijection on 4 bits.
//   stage: LDS chunk c of row r holds src chunk c ^ key4(r)  (dest linear for gload_lds)
//   read:  logical chunk (2s+half) read at LDS chunk (2s+half) ^ key4(row)
// 16-lane group: key4 bijective over r31 0..15 -> 16 distinct chunks -> conflict-free.
// MODE 0: fp32 out, +bias                                  (out-proj)
// MODE 1: bf16 out, +bias; blocks bx>=16 write V^T into vt (QKV + transpose)
// MODE 2: bf16 out = exp((mask? -1e20 : val)/32); fp32 row sums atomically into sums
// MODE 3: bf16 out = val / sums[row]                       (PV + softmax normalize)
template<int MODE>
__global__ __launch_bounds__(256, 2) void gemm_bt128(
    const unsigned short* __restrict__ A, long lda, long strideA,
    const unsigned short* __restrict__ B, long ldb, long strideB,
    void* __restrict__ Cv, long ldc, long strideC,
    const float* __restrict__ bias, const int* __restrict__ mask,
    float* __restrict__ sums, unsigned short* __restrict__ vt, int K) {
  __shared__ unsigned short sA[128 * 128];   // 32 KB
  __shared__ unsigned short sB[128 * 128];   // 32 KB
  const int t = threadIdx.x;
  const int lane = t & 63;
  const int wave = t >> 6;

  const int bx = blockIdx.x, by = blockIdx.y, bz = blockIdx.z;

  const unsigned short* Ab = A + (size_t)bz * strideA + (size_t)by * 128 * lda;
  const unsigned short* Bb = B + (size_t)bz * strideB + (size_t)bx * 128 * ldb;

  // staging: rows of 128 bf16 = 256 B = 16 chunks of 16 B. thread t -> row t>>4 (+o*16),
  // chunk (t&15) pre-swizzled by key4(row) (row bits 0-3 == srow bits 0-3, o*16 safe).
  const int srow = t >> 4;                                  // 0..15
  const int key4s = ((srow & 1) << 3) | ((srow >> 1) & 7);
  const int schunk = (t & 15) ^ key4s;
  const unsigned short* aptr = Ab + (size_t)srow * lda + schunk * 8;
  const unsigned short* bptr = Bb + (size_t)srow * ldb + schunk * 8;
  char* ldsA0 = (char*)&sA[0] + wave * 1024;   // wave-linear dest: + o*4096
  char* ldsB0 = (char*)&sB[0] + wave * 1024;

  f32x16 acc[2][2];
#pragma unroll
  for (int i = 0; i < 2; i++)
#pragma unroll
    for (int j = 0; j < 2; j++)
#pragma unroll
      for (int r = 0; r < 16; r++) acc[i][j][r] = 0.f;

  const int wm = (wave >> 1) * 64;
  const int wn = (wave & 1) * 64;
  const int r31 = lane & 31;
  const int half = lane >> 5;
  const int key4 = ((r31 & 1) << 3) | ((r31 >> 1) & 7);   // = key4(row): row bits 0-3 = r31 bits 0-3

  int chunkOff[8];
#pragma unroll
  for (int s = 0; s < 8; s++) chunkOff[s] = (((2 * s + half) ^ key4) << 4);
  int rowA[2], rowB[2];
#pragma unroll
  for (int i = 0; i < 2; i++) {
    rowA[i] = (wm + i * 32 + r31) << 8;   // *256 B per row
    rowB[i] = (wn + i * 32 + r31) << 8;
  }

  for (int k0 = 0; k0 < K; k0 += 128) {
    __syncthreads();
#pragma unroll
    for (int o = 0; o < 8; o++) {
      __builtin_amdgcn_global_load_lds((AS1 void*)(aptr + (size_t)o * 16 * lda + k0),
                                       (AS3 void*)(ldsA0 + o * 4096), 16, 0, 0);
      __builtin_amdgcn_global_load_lds((AS1 void*)(bptr + (size_t)o * 16 * ldb + k0),
                                       (AS3 void*)(ldsB0 + o * 4096), 16, 0, 0);
    }
    __syncthreads();
#pragma unroll
    for (int s = 0; s < 8; s++) {
      bf16x8 af[2], bfv[2];
#pragma unroll
      for (int i = 0; i < 2; i++) {
        af[i]  = *reinterpret_cast<const bf16x8*>((const char*)sA + rowA[i] + chunkOff[s]);
        bfv[i] = *reinterpret_cast<const bf16x8*>((const char*)sB + rowB[i] + chunkOff[s]);
      }
#pragma unroll
      for (int i = 0; i < 2; i++)
#pragma unroll
        for (int j = 0; j < 2; j++)
          acc[i][j] = __builtin_amdgcn_mfma_f32_32x32x16_bf16(af[i], bfv[j], acc[i][j], 0, 0, 0);
    }
  }

  // ---- epilogue (verified layout: col = lane&31 -> n, row = (r&3)+8*(r>>2)+4*half) ----
  const int* mrow = (MODE == 2) ? (mask + (size_t)bz * 2048) : nullptr;
  const bool vblock = (MODE == 1) && (bx >= 16);  // QKV: n>=2048 is the V third
  float rs[2][16];  // MODE 2: per-lane partial row sums

#pragma unroll
  for (int i = 0; i < 2; i++) {
    int gmb = by * 128 + wm + i * 32;
    float inv_r[16];
    if (MODE == 3) {
#pragma unroll
      for (int r = 0; r < 16; r++) {
        int row = (r & 3) + 8 * (r >> 2) + 4 * half;
        inv_r[r] = 1.0f / sums[(size_t)bz * 2048 + gmb + row];
      }
    }
    if (MODE == 2) {
#pragma unroll
      for (int r = 0; r < 16; r++) rs[i][r] = 0.f;
    }
#pragma unroll
    for (int j = 0; j < 2; j++) {
      int gn = bx * 128 + wn + j * 32 + r31;
      float bv = (MODE == 0 || MODE == 1) ? bias[gn] : 0.0f;
      if (MODE == 1 && vblock) {
        // write V^T: Vt[b][d][s], d = gn-2048, s = gmb+row
        int b = gmb >> 11;
        int sbase = gmb & 2047;
        int d = gn - 2048;
        unsigned short* vp = vt + (size_t)b * 1024 * 2048 + (size_t)d * 2048 + sbase + 4 * half;
#pragma unroll
        for (int qd = 0; qd < 4; qd++) {
          ushort4 o;
          o.x = f2bf(acc[i][j][4 * qd + 0] + bv);
          o.y = f2bf(acc[i][j][4 * qd + 1] + bv);
          o.z = f2bf(acc[i][j][4 * qd + 2] + bv);
          o.w = f2bf(acc[i][j][4 * qd + 3] + bv);
          *reinterpret_cast<ushort4*>(vp + 8 * qd) = o;
        }
      } else {
        bool msk = (MODE == 2) ? (mrow[gn] == 0) : false;
#pragma unroll
        for (int r = 0; r < 16; r++) {
          int row = (r & 3) + 8 * (r >> 2) + 4 * half;
          float val = acc[i][j][r] + bv;
          size_t off = (size_t)bz * strideC + (size_t)(gmb + row) * ldc + gn;
          if (MODE == 2) {
            if (msk) val = -1e20f;
            val = __expf(val * 0.03125f);  // mask BEFORE 1/sqrt(1024) scale, per ref
            rs[i][r] += val;
            ((unsigned short*)Cv)[off] = f2bf(val);
          } else if (MODE == 3) {
            ((unsigned short*)Cv)[off] = f2bf(val * inv_r[r]);
          } else if (MODE == 1) {
            ((unsigned short*)Cv)[off] = f2bf(val);
          } else {
            ((float*)Cv)[off] = val;
          }
        }
      }
    }
  }

  if (MODE == 2) {
    // reduce rs over the 32 column-lanes (r31), then one atomicAdd per row.
    float* srow2 = sums + (size_t)bz * 2048;
#pragma unroll
    for (int i = 0; i < 2; i++) {
      int gmb = by * 128 + wm + i * 32;
#pragma unroll
      for (int r = 0; r < 16; r++) {
        float v = rs[i][r];
#pragma unroll
        for (int o = 16; o >= 1; o >>= 1) v += __shfl_xor(v, o, 64);
        if (r31 == 0) {
          int row = (r & 3) + 8 * (r >> 2) + 4 * half;
          atomicAdd(&srow2[gmb + row], v);
        }
      }
    }
  }
}

extern "C" void kernel_launch(void* const* d_in, const int* in_sizes, int n_in,
                              void* d_out, int out_size, void* d_ws, size_t ws_size,
                              hipStream_t stream) {
  const float* X = (const float*)d_in[0];
  const int* mask = (const int*)d_in[1];
  const float* W_in = (const float*)d_in[2];
  const float* b_in = (const float*)d_in[3];
  const float* W_out = (const float*)d_in[4];
  const float* b_out = (const float*)d_in[5];
  float* out = (float*)d_out;

  const int S = 2048, D = 1024;
  // ws layout (bytes):
  //   Xb  [8192x1024] bf16  16777216  (reused as Ob after QKV)
  //   Wib [3072x1024] bf16   6291456
  //   Wob [1024x1024] bf16   2097152
  //   QK  [8192x2048] bf16  33554432  (Q cols 0..1023, K cols 1024..2047)
  //   P   [4x2048x2048] bf16 33554432 (unnormalized exp weights)
  //   Vt  [4x1024x2048] bf16 16777216
  //   sums[8192] f32            32768
  char* w = (char*)d_ws;
  unsigned short* Xb  = (unsigned short*)w;
  unsigned short* Wib = (unsigned short*)(w + 16777216);
  unsigned short* Wob = (unsigned short*)(w + 16777216 + 6291456);
  unsigned short* QK  = (unsigned short*)(w + 25165824);
  unsigned short* P   = (unsigned short*)(w + 58720256);
  unsigned short* Vt  = (unsigned short*)(w + 92274688);
  float*          sums = (float*)(w + 109051904);
  unsigned short* Ob  = Xb;

  // zero the row-sum accumulators (ws is re-poisoned before every call)
  hipMemsetAsync(sums, 0, 8192 * sizeof(float), stream);

  // one merged cast: X, W_in, W_out -> bf16 (outputs contiguous), grid-stride
  cast_all_kernel<<<2048, 256, 0, stream>>>(X, W_in, W_out, Xb);

  // QKV = Xb @ W_in^T + b_in; Q,K -> QK[8192x2048], V -> Vt (transposed in epilogue)
  gemm_bt128<1><<<dim3(24, 64, 1), 256, 0, stream>>>(
      Xb, D, 0, Wib, D, 0, QK, 2048, 0, b_in, nullptr, nullptr, Vt, D);
  // P = exp(mask(Q K^T)/32); sums += row sums of fp32 exp  [per batch 2048x2048]
  gemm_bt128<2><<<dim3(16, 16, 4), 256, 0, stream>>>(
      QK, 2048, (long)S * 2048, QK + 1024, 2048, (long)S * 2048,
      P, S, (long)S * S, nullptr, mask, sums, nullptr, D);
  // O = (P @ Vt^T) / sums   [per batch 2048x1024] bf16
  gemm_bt128<3><<<dim3(8, 16, 4), 256, 0, stream>>>(
      P, S, (long)S * S, Vt, S, (long)D * S,
      Ob, D, (long)S * D, nullptr, nullptr, sums, nullptr, S);
  // out = O @ W_out^T + b_out  [8192x1024] fp32
  gemm_bt128<0><<<dim3(8, 64, 1), 256, 0, stream>>>(
      Ob, D, 0, Wob, D, 0, out, D, 0, b_out, nullptr, nullptr, nullptr, D);
}

// Round 8
// 290.302 us; speedup vs baseline: 1.0321x; 1.0321x over previous
//
#include <hip/hip_runtime.h>
#include <stdint.h>

#define AS1 __attribute__((address_space(1)))
#define AS3 __attribute__((address_space(3)))

typedef __bf16 bf16x8 __attribute__((ext_vector_type(8)));
typedef float f32x16 __attribute__((ext_vector_type(16)));

__device__ __forceinline__ unsigned short f2bf(float f) {
  unsigned u = __float_as_uint(f);
  u += 0x7FFF + ((u >> 16) & 1);   // round-to-nearest-even
  return (unsigned short)(u >> 16);
}

// ---------------- merged fp32 -> bf16 cast for X, W_in, W_out (grid-stride) ----------------
__global__ __launch_bounds__(256) void cast_all_kernel(const float* __restrict__ X,
                                                       const float* __restrict__ Wi,
                                                       const float* __restrict__ Wo,
                                                       unsigned short* __restrict__ out) {
  const int c1 = 2097152;            // X groups of 4
  const int c2 = 786432;             // W_in groups
  const int c3 = 262144;             // W_out groups
  const int total = c1 + c2 + c3;
  for (int i = blockIdx.x * 256 + threadIdx.x; i < total; i += 2048 * 256) {
    const float* src;
    int j = i;
    if (i < c1) src = X;
    else if (i < c1 + c2) { src = Wi; j = i - c1; }
    else { src = Wo; j = i - c1 - c2; }
    float4 v = reinterpret_cast<const float4*>(src)[j];
    ushort4 o;
    o.x = f2bf(v.x); o.y = f2bf(v.y); o.z = f2bf(v.z); o.w = f2bf(v.w);
    reinterpret_cast<ushort4*>(out)[i] = o;
  }
}

// ---------------- GEMM-BT 128x128 (R4-proven core, conflict-free swizzle) ----------------
// C[m][n] = sum_k A[m][k]*B[n][k]. BK=64, 4 waves of 2x2 32x32x16 MFMA,
// global_load_lds staging, row-pair XOR chunk swizzle (R4/R7: SQ_LDS_BANK_CONFLICT = 0).
// MINW: min waves/EU for __launch_bounds__. LDS = 32 KB, VGPR ~60 -> hardware supports
// 4 blocks/CU (16 waves). MINW=4 for the grid-rich GEMMs (QKV 1536 blocks, QK^T 1024)
// to double latency-hiding; MINW=2 keeps R4-exact codegen for PV/out-proj (512-block grids).
// MODE 0: fp32 out, +bias                                  (out-proj)
// MODE 1: bf16 out, +bias; blocks bx>=16 write V^T into vt (QKV + transpose)
// MODE 2: bf16 out = exp((mask? -1e20 : val)/32); fp32 row sums atomically into sums
// MODE 3: bf16 out = val / sums[row]                       (PV + softmax normalize)
template<int MODE, int MINW>
__global__ __launch_bounds__(256, MINW) void gemm_bt128(
    const unsigned short* __restrict__ A, long lda, long strideA,
    const unsigned short* __restrict__ B, long ldb, long strideB,
    void* __restrict__ Cv, long ldc, long strideC,
    const float* __restrict__ bias, const int* __restrict__ mask,
    float* __restrict__ sums, unsigned short* __restrict__ vt, int K) {
  __shared__ unsigned short sA[128 * 64];
  __shared__ unsigned short sB[128 * 64];
  const int t = threadIdx.x;
  const int lane = t & 63;
  const int wave = t >> 6;

  const unsigned short* Ab = A + (size_t)blockIdx.z * strideA + (size_t)blockIdx.y * 128 * lda;
  const unsigned short* Bb = B + (size_t)blockIdx.z * strideB + (size_t)blockIdx.x * 128 * ldb;

  const int srow = t >> 3;
  const int schunk = (t & 7) ^ ((srow >> 1) & 7);   // conflict-free row-pair swizzle
  const unsigned short* aptr = Ab + (size_t)srow * lda + schunk * 8;
  const unsigned short* bptr = Bb + (size_t)srow * ldb + schunk * 8;
  char* ldsA0 = (char*)&sA[0] + wave * 1024;
  char* ldsB0 = (char*)&sB[0] + wave * 1024;

  f32x16 acc[2][2];
#pragma unroll
  for (int i = 0; i < 2; i++)
#pragma unroll
    for (int j = 0; j < 2; j++)
#pragma unroll
      for (int r = 0; r < 16; r++) acc[i][j][r] = 0.f;

  const int wm = (wave >> 1) * 64;
  const int wn = (wave & 1) * 64;
  const int r31 = lane & 31;
  const int half = lane >> 5;
  const int swz = (r31 >> 1) & 7;

  int offA[2][4], offB[2][4];
#pragma unroll
  for (int i = 0; i < 2; i++)
#pragma unroll
    for (int s = 0; s < 4; s++) {
      offA[i][s] = (wm + i * 32 + r31) * 128 + (((2 * s + half) ^ swz) * 16);
      offB[i][s] = (wn + i * 32 + r31) * 128 + (((2 * s + half) ^ swz) * 16);
    }

  for (int k0 = 0; k0 < K; k0 += 64) {
    __syncthreads();
#pragma unroll
    for (int o = 0; o < 4; o++) {
      __builtin_amdgcn_global_load_lds((AS1 void*)(aptr + (size_t)o * 32 * lda + k0),
                                       (AS3 void*)(ldsA0 + o * 4096), 16, 0, 0);
      __builtin_amdgcn_global_load_lds((AS1 void*)(bptr + (size_t)o * 32 * ldb + k0),
                                       (AS3 void*)(ldsB0 + o * 4096), 16, 0, 0);
    }
    __syncthreads();
#pragma unroll
    for (int s = 0; s < 4; s++) {
      bf16x8 af[2], bfv[2];
#pragma unroll
      for (int i = 0; i < 2; i++) {
        af[i]  = *reinterpret_cast<const bf16x8*>((const char*)sA + offA[i][s]);
        bfv[i] = *reinterpret_cast<const bf16x8*>((const char*)sB + offB[i][s]);
      }
#pragma unroll
      for (int i = 0; i < 2; i++)
#pragma unroll
        for (int j = 0; j < 2; j++)
          acc[i][j] = __builtin_amdgcn_mfma_f32_32x32x16_bf16(af[i], bfv[j], acc[i][j], 0, 0, 0);
    }
  }

  // ---- epilogue (verified layout: col = lane&31 -> n, row = (r&3)+8*(r>>2)+4*half) ----
  const int* mrow = (MODE == 2) ? (mask + (size_t)blockIdx.z * 2048) : nullptr;
  const bool vblock = (MODE == 1) && (blockIdx.x >= 16);  // QKV: n>=2048 is the V third
  float rs[2][16];  // MODE 2: per-lane partial row sums

#pragma unroll
  for (int i = 0; i < 2; i++) {
    int gmb = blockIdx.y * 128 + wm + i * 32;
    float inv_r[16];
    if (MODE == 3) {
#pragma unroll
      for (int r = 0; r < 16; r++) {
        int row = (r & 3) + 8 * (r >> 2) + 4 * half;
        inv_r[r] = 1.0f / sums[(size_t)blockIdx.z * 2048 + gmb + row];
      }
    }
    if (MODE == 2) {
#pragma unroll
      for (int r = 0; r < 16; r++) rs[i][r] = 0.f;
    }
#pragma unroll
    for (int j = 0; j < 2; j++) {
      int gn = blockIdx.x * 128 + wn + j * 32 + r31;
      float bv = (MODE == 0 || MODE == 1) ? bias[gn] : 0.0f;
      if (MODE == 1 && vblock) {
        // write V^T: Vt[b][d][s], d = gn-2048, s = gmb+row
        int b = gmb >> 11;
        int sbase = gmb & 2047;
        int d = gn - 2048;
        unsigned short* vp = vt + (size_t)b * 1024 * 2048 + (size_t)d * 2048 + sbase + 4 * half;
#pragma unroll
        for (int qd = 0; qd < 4; qd++) {
          ushort4 o;
          o.x = f2bf(acc[i][j][4 * qd + 0] + bv);
          o.y = f2bf(acc[i][j][4 * qd + 1] + bv);
          o.z = f2bf(acc[i][j][4 * qd + 2] + bv);
          o.w = f2bf(acc[i][j][4 * qd + 3] + bv);
          *reinterpret_cast<ushort4*>(vp + 8 * qd) = o;
        }
      } else {
        bool msk = (MODE == 2) ? (mrow[gn] == 0) : false;
#pragma unroll
        for (int r = 0; r < 16; r++) {
          int row = (r & 3) + 8 * (r >> 2) + 4 * half;
          float val = acc[i][j][r] + bv;
          size_t off = (size_t)blockIdx.z * strideC + (size_t)(gmb + row) * ldc + gn;
          if (MODE == 2) {
            if (msk) val = -1e20f;
            val = __expf(val * 0.03125f);  // mask BEFORE 1/sqrt(1024) scale, per ref
            rs[i][r] += val;
            ((unsigned short*)Cv)[off] = f2bf(val);
          } else if (MODE == 3) {
            ((unsigned short*)Cv)[off] = f2bf(val * inv_r[r]);
          } else if (MODE == 1) {
            ((unsigned short*)Cv)[off] = f2bf(val);
          } else {
            ((float*)Cv)[off] = val;
          }
        }
      }
    }
  }

  if (MODE == 2) {
    // reduce rs over the 32 column-lanes (r31), then one atomicAdd per row.
    float* srow2 = sums + (size_t)blockIdx.z * 2048;
#pragma unroll
    for (int i = 0; i < 2; i++) {
      int gmb = blockIdx.y * 128 + wm + i * 32;
#pragma unroll
      for (int r = 0; r < 16; r++) {
        float v = rs[i][r];
#pragma unroll
        for (int o = 16; o >= 1; o >>= 1) v += __shfl_xor(v, o, 64);
        if (r31 == 0) {
          int row = (r & 3) + 8 * (r >> 2) + 4 * half;
          atomicAdd(&srow2[gmb + row], v);
        }
      }
    }
  }
}

extern "C" void kernel_launch(void* const* d_in, const int* in_sizes, int n_in,
                              void* d_out, int out_size, void* d_ws, size_t ws_size,
                              hipStream_t stream) {
  const float* X = (const float*)d_in[0];
  const int* mask = (const int*)d_in[1];
  const float* W_in = (const float*)d_in[2];
  const float* b_in = (const float*)d_in[3];
  const float* W_out = (const float*)d_in[4];
  const float* b_out = (const float*)d_in[5];
  float* out = (float*)d_out;

  const int S = 2048, D = 1024;
  // ws layout (bytes):
  //   Xb  [8192x1024] bf16  16777216  (reused as Ob after QKV)
  //   Wib [3072x1024] bf16   6291456
  //   Wob [1024x1024] bf16   2097152
  //   QK  [8192x2048] bf16  33554432  (Q cols 0..1023, K cols 1024..2047)
  //   P   [4x2048x2048] bf16 33554432 (unnormalized exp weights)
  //   Vt  [4x1024x2048] bf16 16777216
  //   sums[8192] f32            32768
  char* w = (char*)d_ws;
  unsigned short* Xb  = (unsigned short*)w;
  unsigned short* Wib = (unsigned short*)(w + 16777216);
  unsigned short* Wob = (unsigned short*)(w + 16777216 + 6291456);
  unsigned short* QK  = (unsigned short*)(w + 25165824);
  unsigned short* P   = (unsigned short*)(w + 58720256);
  unsigned short* Vt  = (unsigned short*)(w + 92274688);
  float*          sums = (float*)(w + 109051904);
  unsigned short* Ob  = Xb;

  // zero the row-sum accumulators (ws is re-poisoned before every call)
  hipMemsetAsync(sums, 0, 8192 * sizeof(float), stream);

  // one merged cast: X, W_in, W_out -> bf16 (outputs contiguous), grid-stride
  cast_all_kernel<<<2048, 256, 0, stream>>>(X, W_in, W_out, Xb);

  // QKV = Xb @ W_in^T + b_in; Q,K -> QK[8192x2048], V -> Vt (transposed in epilogue)
  // 1536 blocks -> 4 blocks/CU occupancy target (MINW=4)
  gemm_bt128<1, 4><<<dim3(24, 64, 1), 256, 0, stream>>>(
      Xb, D, 0, Wib, D, 0, QK, 2048, 0, b_in, nullptr, nullptr, Vt, D);
  // P = exp(mask(Q K^T)/32); sums += row sums of fp32 exp  [per batch 2048x2048]
  // 1024 blocks -> 4 blocks/CU occupancy target (MINW=4)
  gemm_bt128<2, 4><<<dim3(16, 16, 4), 256, 0, stream>>>(
      QK, 2048, (long)S * 2048, QK + 1024, 2048, (long)S * 2048,
      P, S, (long)S * S, nullptr, mask, sums, nullptr, D);
  // O = (P @ Vt^T) / sums   [per batch 2048x1024] bf16  (512 blocks -> MINW=2, R4-exact)
  gemm_bt128<3, 2><<<dim3(8, 16, 4), 256, 0, stream>>>(
      P, S, (long)S * S, Vt, S, (long)D * S,
      Ob, D, (long)S * D, nullptr, nullptr, sums, nullptr, S);
  // out = O @ W_out^T + b_out  [8192x1024] fp32  (512 blocks -> MINW=2, R4-exact)
  gemm_bt128<0, 2><<<dim3(8, 64, 1), 256, 0, stream>>>(
      Ob, D, 0, Wob, D, 0, out, D, 0, b_out, nullptr, nullptr, nullptr, D);
}